// Round 1
// 547.974 us; speedup vs baseline: 1.4553x; 1.4553x over previous
//
#include <hip/hip_runtime.h>
#include <cstddef>

#define B_ 2
#define S_ 2048
#define E_ 768
#define H_ 12
#define D_ 64
#define M_ (B_*S_)   // 4096 rows of x

typedef float f4 __attribute__((ext_vector_type(4)));
typedef short short8 __attribute__((ext_vector_type(8)));

// fp32 -> bf16 (RNE, bit pattern as short)
__device__ __forceinline__ short f2bf(float f) {
    union { float f; unsigned u; } v; v.f = f;
    unsigned r = (v.u + 0x7fffu + ((v.u >> 16) & 1u)) >> 16;
    return (short)r;
}

// ---------------------------------------------------------------------------
// Prep 1: fp32 -> bf16 elementwise (x -> xb). 8 elems/thread, coalesced.
// ---------------------------------------------------------------------------
__global__ __launch_bounds__(256) void cvt_bf16_k(const float* __restrict__ in,
                                                  short* __restrict__ out, int n8)
{
    int i = blockIdx.x * 256 + threadIdx.x;
    if (i >= n8) return;
    f4 a = *(const f4*)(in + (size_t)i * 8);
    f4 b = *(const f4*)(in + (size_t)i * 8 + 4);
    short8 o;
    o[0] = f2bf(a[0]); o[1] = f2bf(a[1]); o[2] = f2bf(a[2]); o[3] = f2bf(a[3]);
    o[4] = f2bf(b[0]); o[5] = f2bf(b[1]); o[6] = f2bf(b[2]); o[7] = f2bf(b[3]);
    *(short8*)(out + (size_t)i * 8) = o;
}

// ---------------------------------------------------------------------------
// Prep 2: W[k][n] fp32 -> Wt[n][k] bf16, all four weight matrices (z-select).
// 32x32 LDS tiles, +1 pad, both global sides coalesced.
// ---------------------------------------------------------------------------
__global__ __launch_bounds__(256) void wtrans_k(const float* __restrict__ Wq,
                                                const float* __restrict__ Wk,
                                                const float* __restrict__ Wv,
                                                const float* __restrict__ Wo,
                                                short* __restrict__ Wt)
{
    __shared__ float T[32][33];
    const float* W = (blockIdx.z == 0) ? Wq : (blockIdx.z == 1) ? Wk
                   : (blockIdx.z == 2) ? Wv : Wo;
    short* o = Wt + (size_t)blockIdx.z * E_ * E_;
    const int tx = threadIdx.x & 31, ty = threadIdx.x >> 5;   // ty 0..7
    const int k0 = blockIdx.y * 32, n0 = blockIdx.x * 32;
    #pragma unroll
    for (int i = 0; i < 4; ++i)
        T[ty * 4 + i][tx] = W[(size_t)(k0 + ty * 4 + i) * E_ + n0 + tx];
    __syncthreads();
    #pragma unroll
    for (int i = 0; i < 4; ++i)
        o[(size_t)(n0 + ty * 4 + i) * E_ + k0 + tx] = f2bf(T[tx][ty * 4 + i]);
}

// ---------------------------------------------------------------------------
// bf16 MFMA GEMM: out = A[M,768](bf16) @ Wt[n][k](bf16) + bias, fp32 acc.
// 64x64 tile, 4 waves; wave w owns rows w*16..w*16+15, all 64 cols.
// LDS tiles [64 rows][8 short8 chunks], XOR-swizzled chunk c at [r][c^(r&7)]
// (same proven layout/fragment scheme as attn_k below).
// MODE 0: fp32 [M,768]           (output projection)
// MODE 1: bf16 [B,H,S,D] *scale  (Q pre-scaled by 0.125, K scale 1)
// MODE 2: bf16 [B,H,D,S]         (V transposed for PV B-fragments)
// ---------------------------------------------------------------------------
template<int MODE>
__global__ __launch_bounds__(256) void gemm_mfma_k(
    const short* __restrict__ A, const short* __restrict__ Bt,
    const float* __restrict__ bias, float* __restrict__ outf,
    short* __restrict__ outb, float scale)
{
    __shared__ short8 As[64][8];   // 8 KB
    __shared__ short8 Bs[64][8];   // 8 KB
    const int t = threadIdx.x;
    const int w = t >> 6, lane = t & 63, ln = lane & 15, quad = lane >> 4;
    const int m0 = blockIdx.y * 64, n0 = blockIdx.x * 64;

    f4 acc[4];
    #pragma unroll
    for (int i = 0; i < 4; ++i) acc[i] = (f4){0.f, 0.f, 0.f, 0.f};

    for (int k0 = 0; k0 < E_; k0 += 64) {
        __syncthreads();
        #pragma unroll
        for (int i = 0; i < 2; ++i) {
            int c = t + i * 256, r = c >> 3, cc = c & 7;
            As[r][cc ^ (r & 7)] =
                *(const short8*)(A  + (size_t)(m0 + r) * E_ + k0 + cc * 8);
            Bs[r][cc ^ (r & 7)] =
                *(const short8*)(Bt + (size_t)(n0 + r) * E_ + k0 + cc * 8);
        }
        __syncthreads();
        const int ar = w * 16 + ln;
        short8 af0 = As[ar][quad ^ (ar & 7)];
        short8 af1 = As[ar][(quad + 4) ^ (ar & 7)];
        #pragma unroll
        for (int ng = 0; ng < 4; ++ng) {
            int br = ng * 16 + ln;
            short8 bf0 = Bs[br][quad ^ (br & 7)];
            short8 bf1 = Bs[br][(quad + 4) ^ (br & 7)];
            acc[ng] = __builtin_amdgcn_mfma_f32_16x16x32_bf16(af0, bf0, acc[ng], 0, 0, 0);
            acc[ng] = __builtin_amdgcn_mfma_f32_16x16x32_bf16(af1, bf1, acc[ng], 0, 0, 0);
        }
    }

    #pragma unroll
    for (int ng = 0; ng < 4; ++ng) {
        int c = n0 + ng * 16 + ln;
        float bv = bias[c];
        #pragma unroll
        for (int g = 0; g < 4; ++g) {
            int r = m0 + w * 16 + quad * 4 + g;
            float v = acc[ng][g] + bv;
            if (MODE == 0) {
                outf[(size_t)r * E_ + c] = v;
            } else {
                int b = r >> 11, s = r & (S_ - 1);
                int h = c >> 6,  d = c & (D_ - 1);
                if (MODE == 1)
                    outb[((size_t)(b * H_ + h) * S_ + s) * D_ + d] = f2bf(v * scale);
                else
                    outb[((size_t)(b * H_ + h) * D_ + d) * S_ + s] = f2bf(v);
            }
        }
    }
}

// ---------------------------------------------------------------------------
// MFMA flash attention (unchanged except ctx now written as bf16 so the
// output projection is a bf16 MFMA GEMM). Block = 256 thr (4 waves), 64
// q-rows (16/wave), one (b,h). Pass 1: QK^T via mfma_f32_16x16x32_bf16,
// l = sum exp(s-8) (fixed base, exact). Pass 2: recompute scores, write
// normalized P (fp32, required output) and accumulate P@V.
// LDS tiles XOR-swizzled: chunk c of row r at [r][c^(r&7)] -> <=2-way (free).
// ---------------------------------------------------------------------------
__global__ __launch_bounds__(256) void attn_k(
    const short* __restrict__ Qb, const short* __restrict__ Kb,
    const short* __restrict__ Vt, float* __restrict__ P,
    short* __restrict__ ctxb)
{
    __shared__ short8 KT[64][8];     // 8 KB, [key][d-chunk] swizzled
    __shared__ short8 VT[64][8];     // 8 KB, [d][key-chunk] swizzled
    __shared__ short  PT[4][16][72]; // per-wave P tile, stride 72 (16B-aligned)

    const int t    = threadIdx.x;
    const int w    = t >> 6;
    const int lane = t & 63, ln = lane & 15, quad = lane >> 4;
    const int bh   = blockIdx.y;
    const int qr   = blockIdx.x * 64 + w * 16;   // wave's first q row

    const size_t kvbase = (size_t)bh * S_ * D_;  // also == bh*D_*S_ for Vt

    // Q A-fragments (Q pre-scaled by 1/8): lane holds Q[qr+ln][quad*8+j (+32)]
    short8 qf0, qf1;
    {
        const short* qrow = Qb + kvbase + (size_t)(qr + ln) * D_;
        qf0 = *(const short8*)(qrow + quad * 8);
        qf1 = *(const short8*)(qrow + 32 + quad * 8);
    }

    f4 l_acc = {0.f, 0.f, 0.f, 0.f};

    // ---- pass 1: l = sum exp(s - 8) ----
    for (int k0 = 0; k0 < S_; k0 += 64) {
        __syncthreads();
        #pragma unroll
        for (int i = 0; i < 2; ++i) {
            int c = t + i * 256, r = c >> 3, cc = c & 7;
            KT[r][cc ^ (r & 7)] =
                *(const short8*)(Kb + kvbase + (size_t)(k0 + r) * D_ + cc * 8);
        }
        __syncthreads();
        #pragma unroll
        for (int kg = 0; kg < 4; ++kg) {
            int row = kg * 16 + ln;
            short8 kf0 = KT[row][quad ^ (row & 7)];
            short8 kf1 = KT[row][(quad + 4) ^ (row & 7)];
            f4 sc = {0.f, 0.f, 0.f, 0.f};
            sc = __builtin_amdgcn_mfma_f32_16x16x32_bf16(qf0, kf0, sc, 0, 0, 0);
            sc = __builtin_amdgcn_mfma_f32_16x16x32_bf16(qf1, kf1, sc, 0, 0, 0);
            #pragma unroll
            for (int g = 0; g < 4; ++g) l_acc[g] += __expf(sc[g] - 8.0f);
        }
    }

    // reduce l over the 16 lanes of each quad (they share rows quad*4+g)
    f4 inv_l;
    #pragma unroll
    for (int g = 0; g < 4; ++g) {
        float v = l_acc[g];
        v += __shfl_xor(v, 1, 64);
        v += __shfl_xor(v, 2, 64);
        v += __shfl_xor(v, 4, 64);
        v += __shfl_xor(v, 8, 64);
        inv_l[g] = 1.0f / v;
    }

    f4 acc[4];
    #pragma unroll
    for (int dg = 0; dg < 4; ++dg) acc[dg] = (f4){0.f, 0.f, 0.f, 0.f};

    float* Pw = P + ((size_t)bh * S_ + qr) * S_;

    // ---- pass 2: normalized P out + P@V ----
    for (int k0 = 0; k0 < S_; k0 += 64) {
        __syncthreads();
        #pragma unroll
        for (int i = 0; i < 2; ++i) {
            int c = t + i * 256, r = c >> 3, cc = c & 7;
            KT[r][cc ^ (r & 7)] =
                *(const short8*)(Kb + kvbase + (size_t)(k0 + r) * D_ + cc * 8);
            VT[r][cc ^ (r & 7)] =
                *(const short8*)(Vt + kvbase + (size_t)r * S_ + k0 + cc * 8);
        }
        __syncthreads();
        #pragma unroll
        for (int kg = 0; kg < 4; ++kg) {
            int row = kg * 16 + ln;
            short8 kf0 = KT[row][quad ^ (row & 7)];
            short8 kf1 = KT[row][(quad + 4) ^ (row & 7)];
            f4 sc = {0.f, 0.f, 0.f, 0.f};
            sc = __builtin_amdgcn_mfma_f32_16x16x32_bf16(qf0, kf0, sc, 0, 0, 0);
            sc = __builtin_amdgcn_mfma_f32_16x16x32_bf16(qf1, kf1, sc, 0, 0, 0);
            #pragma unroll
            for (int g = 0; g < 4; ++g) {
                float p = __expf(sc[g] - 8.0f) * inv_l[g];
                Pw[(size_t)(quad * 4 + g) * S_ + k0 + kg * 16 + ln] = p;
                PT[w][quad * 4 + g][kg * 16 + ln] = f2bf(p);
            }
        }
        __syncthreads();   // make PT visible (also orders vs next staging)
        short8 af0 = *(const short8*)&PT[w][ln][quad * 8];
        short8 af1 = *(const short8*)&PT[w][ln][32 + quad * 8];
        #pragma unroll
        for (int dg = 0; dg < 4; ++dg) {
            int row = dg * 16 + ln;
            short8 vf0 = VT[row][quad ^ (row & 7)];
            short8 vf1 = VT[row][(quad + 4) ^ (row & 7)];
            acc[dg] = __builtin_amdgcn_mfma_f32_16x16x32_bf16(af0, vf0, acc[dg], 0, 0, 0);
            acc[dg] = __builtin_amdgcn_mfma_f32_16x16x32_bf16(af1, vf1, acc[dg], 0, 0, 0);
        }
    }

    // ctx in bf16 [B,S,E] so the output projection is a bf16 MFMA GEMM
    const int b = bh / H_, h = bh % H_;
    #pragma unroll
    for (int dg = 0; dg < 4; ++dg)
        #pragma unroll
        for (int g = 0; g < 4; ++g)
            ctxb[(size_t)(b * S_ + qr + quad * 4 + g) * E_ + h * D_ + dg * 16 + ln]
                = f2bf(acc[dg][g]);
}

// ---------------------------------------------------------------------------
extern "C" void kernel_launch(void* const* d_in, const int* in_sizes, int n_in,
                              void* d_out, int out_size, void* d_ws, size_t ws_size,
                              hipStream_t stream) {
    const float* x  = (const float*)d_in[0];
    const float* Wq = (const float*)d_in[1];
    const float* bq = (const float*)d_in[2];
    const float* Wk = (const float*)d_in[3];
    const float* bk = (const float*)d_in[4];
    const float* Wv = (const float*)d_in[5];
    const float* bv = (const float*)d_in[6];
    const float* Wo = (const float*)d_in[7];
    const float* bo = (const float*)d_in[8];

    const size_t NE = (size_t)M_ * E_;       // 3,145,728
    const size_t W2 = (size_t)E_ * E_;       // 589,824
    short* xb  = (short*)d_ws;               // bf16 x       [M,768]
    short* Wt  = xb + NE;                    // bf16 Wt[4]   [768 n][768 k]
    short* Qb  = Wt + 4 * W2;                // bf16 [B,H,S,D], pre-scaled 1/8
    short* Kb  = Qb + NE;                    // bf16 [B,H,S,D]
    short* Vtb = Kb + NE;                    // bf16 [B,H,D,S]
    short* Cb  = Vtb + NE;                   // bf16 ctx [B,S,E]

    float* out0  = (float*)d_out;            // [B,S,E]
    float* attnw = out0 + NE;                // [B,H,S,S]

    cvt_bf16_k<<<dim3((int)(NE / 8 / 256)), 256, 0, stream>>>(x, xb, (int)(NE / 8));
    wtrans_k<<<dim3(24, 24, 4), 256, 0, stream>>>(Wq, Wk, Wv, Wo, Wt);

    dim3 gg(E_ / 64, M_ / 64);               // (12, 64)
    gemm_mfma_k<1><<<gg, 256, 0, stream>>>(xb, Wt + 0 * W2, bq, nullptr, Qb, 0.125f);
    gemm_mfma_k<1><<<gg, 256, 0, stream>>>(xb, Wt + 1 * W2, bk, nullptr, Kb, 1.0f);
    gemm_mfma_k<2><<<gg, 256, 0, stream>>>(xb, Wt + 2 * W2, bv, nullptr, Vtb, 1.0f);
    attn_k<<<dim3(S_ / 64, B_ * H_), 256, 0, stream>>>(Qb, Kb, Vtb, attnw, Cb);
    gemm_mfma_k<0><<<gg, 256, 0, stream>>>(Cb, Wt + 3 * W2, bo, out0, nullptr, 1.0f);
}